// Round 4
// baseline (381.623 us; speedup 1.0000x reference)
//
#include <hip/hip_runtime.h>
#include <hip/hip_cooperative_groups.h>
#include <stdint.h>

namespace cg = cooperative_groups;

#define H_ 192
#define W_ 192
#define C_ 64
#define EPS_F 1e-8f
#define TILE 16
#define NTX (W_/TILE)
#define NTY (H_/TILE)
#define CHUNK 256
#define NSLICE 4
#define NB (NTX*NTY*NSLICE)   // 576 blocks, 256 thr: co-resident on 256 CUs
#define NBUCKET 256
#define MAXCHUNK 64

typedef unsigned long long ull;

// Output layout (floats), concatenated in reference return order:
// feats (H*W*C) | p2f (H*W) | zbuf (H*W) | bary (H*W*3) | dists (H*W)
#define OFF_FEATS 0
#define OFF_P2F   (H_*W_*C_)
#define OFF_ZBUF  (OFF_P2F + H_*W_)
#define OFF_BARY  (OFF_ZBUF + H_*W_)
#define OFF_DIST  (OFF_BARY + H_*W_*3)

// IEEE-exact ops (block FMA contraction; match numpy float32 op-for-op)
__device__ __forceinline__ float xm(float a, float b){ return __fmul_rn(a,b); }
__device__ __forceinline__ float xa(float a, float b){ return __fadd_rn(a,b); }
__device__ __forceinline__ float xsb(float a, float b){ return __fsub_rn(a,b); }
__device__ __forceinline__ float xd(float a, float b){ return __fdiv_rn(a,b); }

__device__ __forceinline__ float pixcoord(int i, float dim){
    float t = xa(xm(2.0f, (float)i), 1.0f);
    return xsb(1.0f, xd(t, dim));
}

// monotone float<->uint encode for signed-float atomic min/max
__device__ __forceinline__ unsigned fenc(float f){
    unsigned b = __float_as_uint(f);
    return (b & 0x80000000u) ? ~b : (b | 0x80000000u);
}
__device__ __forceinline__ float fdec(unsigned e){
    unsigned b = (e & 0x80000000u) ? (e & 0x7FFFFFFFu) : ~e;
    return __uint_as_float(b);
}

// depth bucket: fixed mapping (perf-only; correctness holds for any mapping)
__device__ __forceinline__ int zbucket(float zmn){
    int b = (int)((zmn - 2.0f) * 64.0f);
    return b < 0 ? 0 : (b > 254 ? 254 : b);
}

// Vertex transform — IDENTICAL op order in every phase (bit-exact recompute).
__device__ __forceinline__ float3 tv(const float* __restrict__ pos,
        const float* __restrict__ K, const float* __restrict__ RT, int i){
    float p0 = pos[3*i+0], p1 = pos[3*i+1], p2 = pos[3*i+2];
    const float sgn[3] = {-1.f, -1.f, 1.f};
    float vv[3];
    #pragma unroll
    for (int j=0;j<3;j++){
        float rp0 = xm(RT[j*4+0], sgn[j]);
        float rp1 = xm(RT[j*4+1], sgn[j]);
        float rp2 = xm(RT[j*4+2], sgn[j]);
        float s = xa(xa(xm(p0,rp0), xm(p1,rp1)), xm(p2,rp2));
        vv[j] = xa(s, xm(RT[j*4+3], sgn[j]));
    }
    float z = vv[2];
    float fx = xd(K[0], 96.0f);
    float fy = xd(K[4], 96.0f);
    float p0x = -xd(xsb(K[2], 96.0f), 96.0f);
    float p0y = -xd(xsb(K[5], 96.0f), 96.0f);
    float xn = xa(xd(xm(fx, vv[0]), z), p0x);
    float yn = xa(xd(xm(fy, vv[1]), z), p0y);
    return make_float3(xn, yn, z);
}

// Shared memory: phases time-share one union (max ~14.6 KB).
union ShMem {
    struct { unsigned lh[NBUCKET]; float wb[16]; } p1;
    struct { unsigned gst[NBUCKET]; unsigned ssc[NBUCKET];
             unsigned lcnt[NBUCKET]; unsigned lbase[NBUCKET]; } p2;
    struct { float lds[CHUNK*12]; float zl[CHUNK]; int slist[CHUNK];
             int wcnt[4]; float suff[MAXCHUNK]; } p3;
};

// Single cooperative kernel: hist+bbox | scan+scatter | raster | shade.
// Record (5 float4), depth-sorted: q0 x0,y0,x1,y1 | q1 x2,y2,z0,z1 |
// q2 z2,ia,fid,zmin | q3 A,B,C,0 | q4 xmn,xmx,ymn,ymx
__global__ __launch_bounds__(256, 3) void k_all(
        const float* __restrict__ pos, const float* __restrict__ feats,
        const int* __restrict__ faces, const float* __restrict__ K,
        const float* __restrict__ RT, float* __restrict__ rec,
        ull* __restrict__ keys, unsigned* __restrict__ hist,
        unsigned* __restrict__ histcur, unsigned* __restrict__ chunkmin,
        unsigned* __restrict__ gbbmin, unsigned* __restrict__ gbbmax,
        float* __restrict__ out, int Fn)
{
    cg::grid_group grid = cg::this_grid();
    __shared__ ShMem sh;
    int t = threadIdx.x, B = blockIdx.x;
    int nfb = (Fn + 255) >> 8;
    int nchunk = (Fn + CHUNK - 1) / CHUNK;

    // ---------------- Phase 1: bucket histogram + global bbox ----------------
    if (B < nfb){
        sh.p1.lh[t] = 0u;
        __syncthreads();
        int f = B*256 + t;
        float bxmn=INFINITY, bxmx=-INFINITY, bymn=INFINITY, bymx=-INFINITY;
        if (f < Fn){
            int i0 = faces[3*f+0], i1 = faces[3*f+1], i2 = faces[3*f+2];
            float3 v0 = tv(pos,K,RT,i0), v1 = tv(pos,K,RT,i1), v2 = tv(pos,K,RT,i2);
            float area = xsb(xm(xsb(v1.x,v0.x), xsb(v2.y,v0.y)), xm(xsb(v1.y,v0.y), xsb(v2.x,v0.x)));
            bool ok = (area > EPS_F) && (v0.z > 0.f) && (v1.z > 0.f) && (v2.z > 0.f);
            int b = 255;
            if (ok){
                float zmn = fminf(v0.z, fminf(v1.z, v2.z));
                b = zbucket(zmn);
                bxmn = fminf(v0.x, fminf(v1.x, v2.x)) - 1e-4f;
                bxmx = fmaxf(v0.x, fmaxf(v1.x, v2.x)) + 1e-4f;
                bymn = fminf(v0.y, fminf(v1.y, v2.y)) - 1e-4f;
                bymx = fmaxf(v0.y, fmaxf(v1.y, v2.y)) + 1e-4f;
            }
            atomicAdd(&sh.p1.lh[b], 1u);
        }
        #pragma unroll
        for (int s2=1; s2<64; s2<<=1){
            bxmn = fminf(bxmn, __shfl_xor(bxmn, s2, 64));
            bxmx = fmaxf(bxmx, __shfl_xor(bxmx, s2, 64));
            bymn = fminf(bymn, __shfl_xor(bymn, s2, 64));
            bymx = fmaxf(bymx, __shfl_xor(bymx, s2, 64));
        }
        if ((t & 63) == 0){
            int w = t >> 6;
            sh.p1.wb[w*4+0]=bxmn; sh.p1.wb[w*4+1]=bxmx;
            sh.p1.wb[w*4+2]=bymn; sh.p1.wb[w*4+3]=bymx;
        }
        __syncthreads();
        if (t == 0){
            float* wb = sh.p1.wb;
            float a0 = fminf(fminf(wb[0],wb[4]),  fminf(wb[8], wb[12]));
            float a1 = fmaxf(fmaxf(wb[1],wb[5]),  fmaxf(wb[9], wb[13]));
            float a2 = fminf(fminf(wb[2],wb[6]),  fminf(wb[10],wb[14]));
            float a3 = fmaxf(fmaxf(wb[3],wb[7]),  fmaxf(wb[11],wb[15]));
            atomicMin(&gbbmin[0], fenc(a0));
            atomicMax(&gbbmax[0], fenc(a1));
            atomicMin(&gbbmin[1], fenc(a2));
            atomicMax(&gbbmax[1], fenc(a3));
        }
        unsigned cc = sh.p1.lh[t];
        if (cc) atomicAdd(&hist[t], cc);   // <= nfb contenders per address
    }
    grid.sync();

    // ---------------- Phase 2: scan (per-block, from summed hist) + scatter ----------------
    if (B < nfb){
        unsigned hv = hist[t];
        sh.p2.ssc[t] = hv;
        sh.p2.lcnt[t] = 0u;
        __syncthreads();
        for (int d=1; d<NBUCKET; d<<=1){
            unsigned u = (t >= d) ? sh.p2.ssc[t-d] : 0u;
            __syncthreads();
            sh.p2.ssc[t] += u;
            __syncthreads();
        }
        sh.p2.gst[t] = sh.p2.ssc[t] - hv;   // exclusive global bucket start
        __syncthreads();
        int f = B*256 + t;
        bool valid = (f < Fn);
        float x0=0,y0=0,z0=0,x1=0,y1=0,z1=0,x2=0,y2=0,z2=0;
        float inv_area=0, xmn=INFINITY, xmx=-INFINITY, ymn=INFINITY, ymx=-INFINITY, zmn=INFINITY;
        float Ap=0.f, Bp=0.f, Cp=0.f;
        int b = 255; unsigned rank = 0;
        if (valid){
            int i0 = faces[3*f+0], i1 = faces[3*f+1], i2 = faces[3*f+2];
            float3 v0 = tv(pos,K,RT,i0), v1 = tv(pos,K,RT,i1), v2 = tv(pos,K,RT,i2);
            x0=v0.x;y0=v0.y;z0=v0.z; x1=v1.x;y1=v1.y;z1=v1.z; x2=v2.x;y2=v2.y;z2=v2.z;
            float area = xsb(xm(xsb(x1,x0), xsb(y2,y0)), xm(xsb(y1,y0), xsb(x2,x0)));
            bool ok = (area > EPS_F) && (z0 > 0.f) && (z1 > 0.f) && (z2 > 0.f);
            inv_area = ok ? xd(1.0f, area) : 0.0f;
            if (ok){
                xmn = fminf(x0, fminf(x1, x2)) - 1e-4f;
                xmx = fmaxf(x0, fmaxf(x1, x2)) + 1e-4f;
                ymn = fminf(y0, fminf(y1, y2)) - 1e-4f;
                ymx = fmaxf(y0, fmaxf(y1, y2)) + 1e-4f;
                zmn = fminf(z0, fminf(z1, z2));
                b = zbucket(zmn);
                // 1/zp = C + A*px + B*py  (filter-only; margins absorb FP error)
                float iz0 = 1.f/z0, iz1 = 1.f/z1, iz2 = 1.f/z2;
                Ap = inv_area * ((y1-y2)*iz0 + (y2-y0)*iz1 + (y0-y1)*iz2);
                Bp = inv_area * ((x2-x1)*iz0 + (x0-x2)*iz1 + (x1-x0)*iz2);
                Cp = inv_area * ((x1*y2-x2*y1)*iz0 + (x2*y0-x0*y2)*iz1 + (x0*y1-x1*y0)*iz2);
            }
            rank = atomicAdd(&sh.p2.lcnt[b], 1u);   // LDS intra-block rank
        }
        __syncthreads();
        unsigned add = sh.p2.lcnt[t];
        if (add) sh.p2.lbase[t] = atomicAdd(&histcur[t], add);  // one per (block,bucket)
        __syncthreads();
        if (valid){
            unsigned p = sh.p2.gst[b] + sh.p2.lbase[b] + rank;  // unique depth-sorted slot
            float4* q = (float4*)(rec + (size_t)p*20);
            q[0] = make_float4(x0, y0, x1, y1);
            q[1] = make_float4(x2, y2, z0, z1);
            q[2] = make_float4(z2, inv_area, __int_as_float(f), zmn);
            q[3] = make_float4(Ap, Bp, Cp, 0.f);
            q[4] = make_float4(xmn, xmx, ymn, ymx);
            if ((p >> 8) < MAXCHUNK)
                atomicMin(&chunkmin[p >> 8], __float_as_uint(zmn));  // pos floats: uint order == float order
        }
    }
    grid.sync();

    // ---------------- Phase 3: tiled raster (all skips conservative vs FINAL key) ----------------
    {
        int Btile = B % (NTX*NTY);
        int slice = B / (NTX*NTY);
        int tbx = Btile % NTX, tby = Btile / NTX;
        if (t < MAXCHUNK){
            float v = (t < nchunk) ? __uint_as_float(chunkmin[t]) : INFINITY;
            #pragma unroll
            for (int s=1; s<MAXCHUNK; s<<=1){
                int src = t + s; if (src > MAXCHUNK-1) src = MAXCHUNK-1;
                float o = __shfl(v, src, 64);
                v = fminf(v, o);
            }
            sh.p3.suff[t] = v;   // suffix-min of chunk zmins
        }
        int ix = tbx*TILE + (t & 15);
        int iy = tby*TILE + (t >> 4);
        int pix = iy*W_ + ix;
        float px = pixcoord(ix, (float)W_);
        float py = pixcoord(iy, (float)H_);
        float tx_hi = pixcoord(tbx*TILE,          (float)W_);
        float tx_lo = pixcoord(tbx*TILE + TILE-1, (float)W_);
        float ty_hi = pixcoord(tby*TILE,          (float)H_);
        float ty_lo = pixcoord(tby*TILE + TILE-1, (float)H_);
        float gx0 = fdec(gbbmin[0]), gx1 = fdec(gbbmax[0]);
        float gy0 = fdec(gbbmin[1]), gy1 = fdec(gbbmax[1]);
        bool alive = (px >= gx0) && (px <= gx1) && (py >= gy0) && (py <= gy1);
        int lane = t & 63, wv = t >> 6;

        float zcut = INFINITY;
        ull localkey = 0xFFFFFFFFFFFFFFFFULL;
        ull published = 0xFFFFFFFFFFFFFFFFULL;
        __syncthreads();             // suff[] ready

        for (int c = slice; c < nchunk; c += NSLICE){
            ull g = __hip_atomic_load(&keys[pix], __ATOMIC_RELAXED, __HIP_MEMORY_SCOPE_AGENT);
            float zg = __uint_as_float((unsigned)(g >> 32));   // NaN if empty -> fminf ignores
            zcut = fminf(zcut, zg);
            float sc = (c < MAXCHUNK) ? sh.p3.suff[c] : 0.0f;
            int done = (!alive || !(xm(sc, 0.999f) < zcut)) ? 1 : 0;
            if (__syncthreads_and(done)) break;    // barrier also protects lds reuse

            int fi = c*CHUNK + t;
            float4 q0 = make_float4(0,0,0,0), q1 = q0, q2 = q0;
            bool keep = false;
            float zb = 0.f;
            if (fi < Fn){
                const float4* gq = (const float4*)(rec + (size_t)fi*20);
                q0 = gq[0]; q1 = gq[1]; q2 = gq[2];
                float4 q3 = gq[3], q4 = gq[4];
                keep = (q4.x <= tx_hi) && (q4.y >= tx_lo) && (q4.z <= ty_hi) && (q4.w >= ty_lo);
                if (keep){
                    // tile z lower bound from the linear 1/z plane (corner max + margin)
                    float ax = (q3.x > 0.f) ? tx_hi : tx_lo;
                    float by = (q3.y > 0.f) ? ty_hi : ty_lo;
                    float Nmax = q3.z + q3.x*ax + q3.y*by;
                    float M = fabsf(q3.x*ax) + fabsf(q3.y*by) + fabsf(q3.z);
                    float Nub = Nmax + 1e-5f*M + 1e-30f;
                    if (Nub <= 0.f) keep = false;          // no coverage possible in tile
                    else zb = fmaxf(1.f/Nub, q2.w);        // max(plane bound, face zmin)
                }
            }
            float4* l = (float4*)(sh.p3.lds + t*12);
            l[0] = q0; l[1] = q1; l[2] = q2;
            ull m = __ballot(keep);
            if (lane == 0) sh.p3.wcnt[wv] = __popcll(m);
            __syncthreads();
            int basecnt = 0;
            #pragma unroll
            for (int w2 = 0; w2 < 4; ++w2) if (w2 < wv) basecnt += sh.p3.wcnt[w2];
            if (keep){
                int p = basecnt + __popcll(m & ((1ULL << lane) - 1ULL));
                sh.p3.slist[p] = t;
                sh.p3.zl[p] = zb;
            }
            int nsurv = sh.p3.wcnt[0] + sh.p3.wcnt[1] + sh.p3.wcnt[2] + sh.p3.wcnt[3];
            __syncthreads();

            for (int k = 0; k < nsurv; k++){
                float zbl = sh.p3.zl[k];
                if (!(xm(zbl, 0.999f) < zcut)) continue;   // conservative tile-z pre-check
                int j = sh.p3.slist[k];
                const float* r = sh.p3.lds + j*12;
                float x0=r[0], y0=r[1], x1=r[2], y1=r[3], x2=r[4], y2=r[5];
                float dx0=xsb(x0,px), dx1=xsb(x1,px), dx2=xsb(x2,px);
                float dy0=xsb(y0,py), dy1=xsb(y1,py), dy2=xsb(y2,py);
                float e0 = xsb(xm(dx1,dy2), xm(dy1,dx2));
                float e1 = xsb(xm(dx2,dy0), xm(dy2,dx0));
                float e2 = xsb(xm(dx0,dy1), xm(dy0,dx1));
                if (e0 >= 0.f && e1 >= 0.f && e2 >= 0.f){
                    float z0=r[6], z1=r[7], z2=r[8], ia=r[9];
                    float w0 = xm(e0, ia), w1 = xm(e1, ia), w2 = xm(e2, ia);
                    float l0 = xm(xm(w0,z1),z2);
                    float l1 = xm(xm(z0,w1),z2);
                    float l2 = xm(xm(z0,z1),w2);
                    float s  = xa(xa(l0,l1),l2);
                    // cheap-z filter (1 divide); skip only when provably worse than zcut.
                    float za = (l0*z0 + l1*z1 + l2*z2) / s;
                    if (za*0.99999f >= zcut) continue;
                    float dn = (s == 0.f) ? 1.0f : s;
                    float b0 = fmaxf(xd(l0,dn), 0.f);
                    float b1 = fmaxf(xd(l1,dn), 0.f);
                    float b2 = fmaxf(xd(l2,dn), 0.f);
                    float bs = fmaxf(xa(xa(b0,b1),b2), EPS_F);
                    b0 = xd(b0,bs); b1 = xd(b1,bs); b2 = xd(b2,bs);
                    float zp = xa(xa(xm(b0,z0),xm(b1,z1)),xm(b2,z2));
                    ull ck = (((ull)__float_as_uint(zp)) << 32) | (unsigned)__float_as_int(r[10]);
                    if (ck < localkey) localkey = ck;
                    zcut = fminf(zcut, zp);
                }
            }
            if (localkey < published){     // publish so other slice blocks can break
                atomicMin(&keys[pix], localkey);
                published = localkey;
            }
        }
        if (localkey < published) atomicMin(&keys[pix], localkey);
    }
    grid.sync();

    // ---------------- Phase 4: resolve + shade (64 lanes/pixel, grid-stride) ----------------
    {
        int grp = t >> 6, ch = t & 63;
        float* p2f  = out + OFF_P2F;
        float* zbuf = out + OFF_ZBUF;
        float* bary = out + OFF_BARY;
        float* dist = out + OFF_DIST;
        for (int pix = B*4 + grp; pix < H_*W_; pix += NB*4){
            ull key = keys[pix];
            if (key == 0xFFFFFFFFFFFFFFFFULL){
                out[OFF_FEATS + pix*C_ + ch] = 0.0f;
                if (ch == 0){ p2f[pix] = -1.0f; zbuf[pix] = -1.0f; dist[pix] = -1.0f; }
                if (ch < 3) bary[3*pix+ch] = -1.0f;
            } else {
                int f = (int)(key & 0xFFFFFFFFu);
                float z = __uint_as_float((unsigned)(key >> 32));
                int ix2 = pix % W_, iy2 = pix / W_;
                float px = pixcoord(ix2, (float)W_);
                float py = pixcoord(iy2, (float)H_);
                int i0 = faces[3*f+0], i1 = faces[3*f+1], i2 = faces[3*f+2];
                float3 v0 = tv(pos,K,RT,i0), v1 = tv(pos,K,RT,i1), v2 = tv(pos,K,RT,i2);
                float x0=v0.x,y0=v0.y,z0=v0.z, x1=v1.x,y1=v1.y,z1=v1.z, x2=v2.x,y2=v2.y,z2=v2.z;
                float area = xsb(xm(xsb(x1,x0), xsb(y2,y0)), xm(xsb(y1,y0), xsb(x2,x0)));
                float ia = xd(1.0f, area);   // hit face -> guaranteed ok
                float w0 = xm(xsb(xm(xsb(x1,px),xsb(y2,py)), xm(xsb(y1,py),xsb(x2,px))), ia);
                float w1 = xm(xsb(xm(xsb(x2,px),xsb(y0,py)), xm(xsb(y2,py),xsb(x0,px))), ia);
                float w2 = xm(xsb(xm(xsb(x0,px),xsb(y1,py)), xm(xsb(y0,py),xsb(x1,px))), ia);
                float l0 = xm(xm(w0,z1),z2);
                float l1 = xm(xm(z0,w1),z2);
                float l2 = xm(xm(z0,z1),w2);
                float s  = xa(xa(l0,l1),l2);
                float dn = (s == 0.f) ? 1.0f : s;
                float b0 = fmaxf(xd(l0,dn), 0.f);
                float b1 = fmaxf(xd(l1,dn), 0.f);
                float b2 = fmaxf(xd(l2,dn), 0.f);
                float bs = fmaxf(xa(xa(b0,b1),b2), EPS_F);
                b0 = xd(b0,bs); b1 = xd(b1,bs); b2 = xd(b2,bs);
                float res = xa(xa(xm(b0, feats[i0*C_ + ch]), xm(b1, feats[i1*C_ + ch])),
                               xm(b2, feats[i2*C_ + ch]));
                out[OFF_FEATS + pix*C_ + ch] = res;
                if (ch == 0){ p2f[pix] = (float)f; zbuf[pix] = z; dist[pix] = 0.0f; }
                if (ch < 3){
                    float bb = (ch == 0) ? b0 : ((ch == 1) ? b1 : b2);
                    bary[3*pix+ch] = bb;
                }
            }
        }
    }
}

extern "C" void kernel_launch(void* const* d_in, const int* in_sizes, int n_in,
                              void* d_out, int out_size, void* d_ws, size_t ws_size,
                              hipStream_t stream) {
    const float* positions = (const float*)d_in[0];
    const float* features  = (const float*)d_in[1];
    const int*   faces     = (const int*)  d_in[2];
    const float* K         = (const float*)d_in[3];
    const float* RT        = (const float*)d_in[4];
    int Fn = in_sizes[2] / 3;   // 16384

    // Workspace layout (memset-friendly ordering):
    // region A (0xFF): keys | chunkmin | gbbmin(4)    region B (0x00): hist | histcur | gbbmax(4)
    ull*      keys     = (ull*)d_ws;                    // H*W * 8 B
    unsigned* chunkmin = (unsigned*)(keys + H_*W_);     // 64 words
    unsigned* gbbmin   = chunkmin + MAXCHUNK;           // 4 words (2 used + pad)
    unsigned* hist     = gbbmin + 4;                    // 256 words
    unsigned* histcur  = hist + NBUCKET;                // 256 words
    unsigned* gbbmax   = histcur + NBUCKET;             // 4 words (2 used + pad)
    float*    rec      = (float*)(gbbmax + 4);          // Fn*20 floats (depth-sorted)

    size_t regA = (size_t)H_*W_*sizeof(ull) + MAXCHUNK*4 + 16;
    size_t regB = NBUCKET*4*2 + 16;
    hipMemsetAsync(keys, 0xFF, regA, stream);
    hipMemsetAsync(hist, 0x00, regB, stream);

    float* outp = (float*)d_out;
    void* args[] = { (void*)&positions, (void*)&features, (void*)&faces,
                     (void*)&K, (void*)&RT, (void*)&rec, (void*)&keys,
                     (void*)&hist, (void*)&histcur, (void*)&chunkmin,
                     (void*)&gbbmin, (void*)&gbbmax, (void*)&outp, (void*)&Fn };
    hipLaunchCooperativeKernel(k_all, dim3(NB), dim3(256), args, 0u, stream);
}

// Round 5
// 203.797 us; speedup vs baseline: 1.8726x; 1.8726x over previous
//
#include <hip/hip_runtime.h>
#include <stdint.h>

#define H_ 192
#define W_ 192
#define C_ 64
#define EPS_F 1e-8f
#define TILE 16
#define NTX (W_/TILE)
#define NTY (H_/TILE)
#define CHUNK 256
#define NSLICE 8
#define NBUCKET 256
#define MAXCHUNK 64

typedef unsigned long long ull;

// Output layout (floats), concatenated in reference return order:
// feats (H*W*C) | p2f (H*W) | zbuf (H*W) | bary (H*W*3) | dists (H*W)
#define OFF_FEATS 0
#define OFF_P2F   (H_*W_*C_)
#define OFF_ZBUF  (OFF_P2F + H_*W_)
#define OFF_BARY  (OFF_ZBUF + H_*W_)
#define OFF_DIST  (OFF_BARY + H_*W_*3)

// IEEE-exact ops (block FMA contraction; match numpy float32 op-for-op)
__device__ __forceinline__ float xm(float a, float b){ return __fmul_rn(a,b); }
__device__ __forceinline__ float xa(float a, float b){ return __fadd_rn(a,b); }
__device__ __forceinline__ float xsb(float a, float b){ return __fsub_rn(a,b); }
__device__ __forceinline__ float xd(float a, float b){ return __fdiv_rn(a,b); }

__device__ __forceinline__ float pixcoord(int i, float dim){
    float t = xa(xm(2.0f, (float)i), 1.0f);
    return xsb(1.0f, xd(t, dim));
}

// monotone float<->uint encode for signed-float atomic min/max
__device__ __forceinline__ unsigned fenc(float f){
    unsigned b = __float_as_uint(f);
    return (b & 0x80000000u) ? ~b : (b | 0x80000000u);
}
__device__ __forceinline__ float fdec(unsigned e){
    unsigned b = (e & 0x80000000u) ? (e & 0x7FFFFFFFu) : ~e;
    return __uint_as_float(b);
}

// depth bucket: fixed mapping (perf-only; correctness holds for any mapping)
__device__ __forceinline__ int zbucket(float zmn){
    int b = (int)((zmn - 2.0f) * 64.0f);
    return b < 0 ? 0 : (b > 254 ? 254 : b);
}

// Vertex transform — computed ONCE (k_pre); consumers read the stored bits.
__device__ __forceinline__ float3 tv(const float* __restrict__ pos,
        const float* __restrict__ K, const float* __restrict__ RT, int i){
    float p0 = pos[3*i+0], p1 = pos[3*i+1], p2 = pos[3*i+2];
    const float sgn[3] = {-1.f, -1.f, 1.f};
    float vv[3];
    #pragma unroll
    for (int j=0;j<3;j++){
        float rp0 = xm(RT[j*4+0], sgn[j]);
        float rp1 = xm(RT[j*4+1], sgn[j]);
        float rp2 = xm(RT[j*4+2], sgn[j]);
        float s = xa(xa(xm(p0,rp0), xm(p1,rp1)), xm(p2,rp2));
        vv[j] = xa(s, xm(RT[j*4+3], sgn[j]));
    }
    float z = vv[2];
    float fx = xd(K[0], 96.0f);
    float fy = xd(K[4], 96.0f);
    float p0x = -xd(xsb(K[2], 96.0f), 96.0f);
    float p0y = -xd(xsb(K[5], 96.0f), 96.0f);
    float xn = xa(xd(xm(fx, vv[0]), z), p0x);
    float yn = xa(xd(xm(fy, vv[1]), z), p0y);
    return make_float3(xn, yn, z);
}

// Launch 1 (256 blocks x 64 thr — one face/thread, spread over CUs):
// transform verts once, write unsorted 12-float record rec0[f], LDS histogram
// -> non-returning global adds, wave-reduced global bbox.
// rec0 (3 float4): q0 x0,y0,x1,y1 | q1 x2,y2,z0,z1 | q2 z2,ia,fid,zmin
__global__ __launch_bounds__(64) void k_pre(const float* __restrict__ pos,
        const float* __restrict__ K, const float* __restrict__ RT,
        const int* __restrict__ faces, float* __restrict__ rec0,
        unsigned* __restrict__ hist, unsigned* __restrict__ gbbmin,
        unsigned* __restrict__ gbbmax, int Fn){
    __shared__ unsigned lh[NBUCKET];
    int t = threadIdx.x, B = blockIdx.x;
    #pragma unroll
    for (int i=t; i<NBUCKET; i+=64) lh[i] = 0u;
    __syncthreads();
    int f = B*64 + t;
    float bxmn=INFINITY, bxmx=-INFINITY, bymn=INFINITY, bymx=-INFINITY;
    if (f < Fn){
        int i0 = faces[3*f+0], i1 = faces[3*f+1], i2 = faces[3*f+2];
        float3 v0 = tv(pos,K,RT,i0), v1 = tv(pos,K,RT,i1), v2 = tv(pos,K,RT,i2);
        float area = xsb(xm(xsb(v1.x,v0.x), xsb(v2.y,v0.y)), xm(xsb(v1.y,v0.y), xsb(v2.x,v0.x)));
        bool ok = (area > EPS_F) && (v0.z > 0.f) && (v1.z > 0.f) && (v2.z > 0.f);
        float ia = ok ? xd(1.0f, area) : 0.0f;
        float zmn = INFINITY;
        int b = 255;
        if (ok){
            zmn = fminf(v0.z, fminf(v1.z, v2.z));
            b = zbucket(zmn);
            bxmn = fminf(v0.x, fminf(v1.x, v2.x)) - 1e-4f;
            bxmx = fmaxf(v0.x, fmaxf(v1.x, v2.x)) + 1e-4f;
            bymn = fminf(v0.y, fminf(v1.y, v2.y)) - 1e-4f;
            bymx = fmaxf(v0.y, fmaxf(v1.y, v2.y)) + 1e-4f;
        }
        atomicAdd(&lh[b], 1u);
        float4* q = (float4*)(rec0 + (size_t)f*12);
        q[0] = make_float4(v0.x, v0.y, v1.x, v1.y);
        q[1] = make_float4(v2.x, v2.y, v0.z, v1.z);
        q[2] = make_float4(v2.z, ia, __int_as_float(f), zmn);
    }
    // single-wave bbox reduce -> 4 non-returning atomics per block
    #pragma unroll
    for (int s2=1; s2<64; s2<<=1){
        bxmn = fminf(bxmn, __shfl_xor(bxmn, s2, 64));
        bxmx = fmaxf(bxmx, __shfl_xor(bxmx, s2, 64));
        bymn = fminf(bymn, __shfl_xor(bymn, s2, 64));
        bymx = fmaxf(bymx, __shfl_xor(bymx, s2, 64));
    }
    if (t == 0){
        atomicMin(&gbbmin[0], fenc(bxmn));
        atomicMax(&gbbmax[0], fenc(bxmx));
        atomicMin(&gbbmin[1], fenc(bymn));
        atomicMax(&gbbmax[1], fenc(bymx));
    }
    __syncthreads();
    #pragma unroll
    for (int i=t; i<NBUCKET; i+=64){
        unsigned cc = lh[i];
        if (cc) atomicAdd(&hist[i], cc);   // non-returning, <=256 contenders
    }
}

// Launch 2 (64 blocks x 256): read summed hist, LDS scan, LDS-rank +
// one returning global atomic per (block,bucket), permute rec0 -> depth-sorted
// rec (20 floats: + plane coeffs q3 and bbox q4), chunk zmins.
// rec: q0 x0,y0,x1,y1 | q1 x2,y2,z0,z1 | q2 z2,ia,fid,zmin | q3 A,B,C,0 | q4 xmn,xmx,ymn,ymx
__global__ __launch_bounds__(256) void k_scatter(const float* __restrict__ rec0,
        const unsigned* __restrict__ hist, unsigned* __restrict__ histcur,
        float* __restrict__ rec, unsigned* __restrict__ chunkmin, int Fn){
    __shared__ unsigned gst[NBUCKET], ssc[NBUCKET], lcnt[NBUCKET], lbase[NBUCKET];
    int t = threadIdx.x, B = blockIdx.x;
    unsigned hv = hist[t];
    ssc[t] = hv;
    lcnt[t] = 0u;
    __syncthreads();
    for (int d=1; d<NBUCKET; d<<=1){
        unsigned u = (t >= d) ? ssc[t-d] : 0u;
        __syncthreads();
        ssc[t] += u;
        __syncthreads();
    }
    gst[t] = ssc[t] - hv;   // exclusive global bucket start
    __syncthreads();
    int f = B*256 + t;
    bool valid = (f < Fn);
    float4 q0, q1, q2;
    int b = 255; unsigned rank = 0; bool ok = false; float zmn = INFINITY;
    if (valid){
        const float4* q = (const float4*)(rec0 + (size_t)f*12);
        q0 = q[0]; q1 = q[1]; q2 = q[2];
        ok = (q2.y > 0.f);            // ia > 0 <=> face live
        zmn = q2.w;
        b = ok ? zbucket(zmn) : 255;
        rank = atomicAdd(&lcnt[b], 1u);     // LDS intra-block rank
    }
    __syncthreads();
    unsigned add = lcnt[t];
    if (add) lbase[t] = atomicAdd(&histcur[t], add);  // one per (block,bucket)
    __syncthreads();
    if (valid){
        float x0=q0.x, y0=q0.y, x1=q0.z, y1=q0.w;
        float x2=q1.x, y2=q1.y, z0=q1.z, z1=q1.w;
        float z2=q2.x, ia=q2.y;
        float xmn, xmx, ymn, ymx, Ap=0.f, Bp=0.f, Cp=0.f;
        if (ok){
            xmn = fminf(x0, fminf(x1, x2)) - 1e-4f;
            xmx = fmaxf(x0, fmaxf(x1, x2)) + 1e-4f;
            ymn = fminf(y0, fminf(y1, y2)) - 1e-4f;
            ymx = fmaxf(y0, fmaxf(y1, y2)) + 1e-4f;
            // 1/zp = C + A*px + B*py  (filter-only; margins absorb FP error)
            float iz0 = 1.f/z0, iz1 = 1.f/z1, iz2 = 1.f/z2;
            Ap = ia * ((y1-y2)*iz0 + (y2-y0)*iz1 + (y0-y1)*iz2);
            Bp = ia * ((x2-x1)*iz0 + (x0-x2)*iz1 + (x1-x0)*iz2);
            Cp = ia * ((x1*y2-x2*y1)*iz0 + (x2*y0-x0*y2)*iz1 + (x0*y1-x1*y0)*iz2);
        } else {
            xmn = INFINITY; xmx = -INFINITY; ymn = INFINITY; ymx = -INFINITY;
        }
        unsigned p = gst[b] + lbase[b] + rank;   // unique depth-sorted slot
        float4* qo = (float4*)(rec + (size_t)p*20);
        qo[0] = q0; qo[1] = q1; qo[2] = q2;
        qo[3] = make_float4(Ap, Bp, Cp, 0.f);
        qo[4] = make_float4(xmn, xmx, ymn, ymx);
        if ((p >> 8) < MAXCHUNK)
            atomicMin(&chunkmin[p >> 8], __float_as_uint(zmn));  // pos floats: uint order == float order
    }
}

// Launch 3: tiled raster (1152 blocks). All skips provably conservative vs the
// FINAL key (zcut >= final zbest always), so output is timing-independent.
__global__ __launch_bounds__(256) void k_raster(const float* __restrict__ rec,
        const unsigned* __restrict__ chunkmin, const unsigned* __restrict__ gbbmin,
        const unsigned* __restrict__ gbbmax, ull* __restrict__ keys, int Fn){
    __shared__ float lds[CHUNK*12];
    __shared__ float zl[CHUNK];       // per-tile z lower bound of survivors
    __shared__ int   slist[CHUNK];
    __shared__ int   wcnt[4];
    __shared__ float suff[MAXCHUNK];  // suffix-min of chunk zmins
    int tid = threadIdx.x;
    int nchunk = (Fn + CHUNK - 1) / CHUNK;
    if (tid < MAXCHUNK){
        float v = (tid < nchunk) ? __uint_as_float(chunkmin[tid]) : INFINITY;
        #pragma unroll
        for (int s=1; s<MAXCHUNK; s<<=1){
            int src = tid + s; if (src > MAXCHUNK-1) src = MAXCHUNK-1;
            float o = __shfl(v, src, 64);
            v = fminf(v, o);
        }
        suff[tid] = v;
    }
    int ix = blockIdx.x*TILE + (tid & 15);
    int iy = blockIdx.y*TILE + (tid >> 4);
    int pix = iy*W_ + ix;
    float px = pixcoord(ix, (float)W_);
    float py = pixcoord(iy, (float)H_);
    float tx_hi = pixcoord(blockIdx.x*TILE,          (float)W_);
    float tx_lo = pixcoord(blockIdx.x*TILE + TILE-1, (float)W_);
    float ty_hi = pixcoord(blockIdx.y*TILE,          (float)H_);
    float ty_lo = pixcoord(blockIdx.y*TILE + TILE-1, (float)H_);
    float gx0 = fdec(gbbmin[0]), gx1 = fdec(gbbmax[0]);
    float gy0 = fdec(gbbmin[1]), gy1 = fdec(gbbmax[1]);
    bool alive = (px >= gx0) && (px <= gx1) && (py >= gy0) && (py <= gy1);
    int lane = tid & 63, wv = tid >> 6;

    float zcut = INFINITY;
    ull localkey = 0xFFFFFFFFFFFFFFFFULL;
    ull published = 0xFFFFFFFFFFFFFFFFULL;
    __syncthreads();             // suff[] ready

    for (int c = (int)blockIdx.z; c < nchunk; c += NSLICE){
        // share depth convergence across slice blocks (stale reads conservative)
        ull g = __hip_atomic_load(&keys[pix], __ATOMIC_RELAXED, __HIP_MEMORY_SCOPE_AGENT);
        float zg = __uint_as_float((unsigned)(g >> 32));   // NaN if empty -> fminf ignores
        zcut = fminf(zcut, zg);
        float sc = (c < MAXCHUNK) ? suff[c] : 0.0f;
        int done = (!alive || !(xm(sc, 0.999f) < zcut)) ? 1 : 0;
        if (__syncthreads_and(done)) break;    // barrier also protects lds reuse

        int fi = c*CHUNK + tid;
        float4 q0 = make_float4(0,0,0,0), q1 = q0, q2 = q0;
        bool keep = false;
        float zb = 0.f;
        if (fi < Fn){
            const float4* gq = (const float4*)(rec + (size_t)fi*20);
            q0 = gq[0]; q1 = gq[1]; q2 = gq[2];
            float4 q3 = gq[3], q4 = gq[4];
            keep = (q4.x <= tx_hi) && (q4.y >= tx_lo) && (q4.z <= ty_hi) && (q4.w >= ty_lo);
            if (keep){
                // tile z lower bound from the linear 1/z plane (corner max + margin)
                float ax = (q3.x > 0.f) ? tx_hi : tx_lo;
                float by = (q3.y > 0.f) ? ty_hi : ty_lo;
                float Nmax = q3.z + q3.x*ax + q3.y*by;
                float M = fabsf(q3.x*ax) + fabsf(q3.y*by) + fabsf(q3.z);
                float Nub = Nmax + 1e-5f*M + 1e-30f;
                if (Nub <= 0.f) keep = false;          // no coverage possible in tile
                else zb = fmaxf(1.f/Nub, q2.w);        // max(plane bound, face zmin)
            }
        }
        float4* l = (float4*)(lds + tid*12);
        l[0] = q0; l[1] = q1; l[2] = q2;
        ull m = __ballot(keep);
        if (lane == 0) wcnt[wv] = __popcll(m);
        __syncthreads();
        int basecnt = 0;
        #pragma unroll
        for (int w2 = 0; w2 < 4; ++w2) if (w2 < wv) basecnt += wcnt[w2];
        if (keep){
            int p = basecnt + __popcll(m & ((1ULL << lane) - 1ULL));
            slist[p] = tid;
            zl[p] = zb;
        }
        int nsurv = wcnt[0] + wcnt[1] + wcnt[2] + wcnt[3];
        __syncthreads();

        for (int k = 0; k < nsurv; k++){
            float zbl = zl[k];
            if (!(xm(zbl, 0.999f) < zcut)) continue;   // conservative tile-z pre-check
            int j = slist[k];
            const float* r = lds + j*12;
            float x0=r[0], y0=r[1], x1=r[2], y1=r[3], x2=r[4], y2=r[5];
            float dx0=xsb(x0,px), dx1=xsb(x1,px), dx2=xsb(x2,px);
            float dy0=xsb(y0,py), dy1=xsb(y1,py), dy2=xsb(y2,py);
            float e0 = xsb(xm(dx1,dy2), xm(dy1,dx2));
            float e1 = xsb(xm(dx2,dy0), xm(dy2,dx0));
            float e2 = xsb(xm(dx0,dy1), xm(dy0,dx1));
            if (e0 >= 0.f && e1 >= 0.f && e2 >= 0.f){
                float z0=r[6], z1=r[7], z2=r[8], ia=r[9];
                float w0 = xm(e0, ia), w1 = xm(e1, ia), w2 = xm(e2, ia);
                float l0 = xm(xm(w0,z1),z2);
                float l1 = xm(xm(z0,w1),z2);
                float l2 = xm(xm(z0,z1),w2);
                float s  = xa(xa(l0,l1),l2);
                // cheap-z filter (1 divide); skip only when provably worse than zcut.
                float za = (l0*z0 + l1*z1 + l2*z2) / s;
                if (za*0.99999f >= zcut) continue;
                float dn = (s == 0.f) ? 1.0f : s;
                float b0 = fmaxf(xd(l0,dn), 0.f);
                float b1 = fmaxf(xd(l1,dn), 0.f);
                float b2 = fmaxf(xd(l2,dn), 0.f);
                float bs = fmaxf(xa(xa(b0,b1),b2), EPS_F);
                b0 = xd(b0,bs); b1 = xd(b1,bs); b2 = xd(b2,bs);
                float zp = xa(xa(xm(b0,z0),xm(b1,z1)),xm(b2,z2));
                // packed (z, orig_fid) key: exact argmin-first tie semantics
                ull ck = (((ull)__float_as_uint(zp)) << 32) | (unsigned)__float_as_int(r[10]);
                if (ck < localkey) localkey = ck;
                zcut = fminf(zcut, zp);
            }
        }
        if (localkey < published){     // publish so other slice blocks can break
            atomicMin(&keys[pix], localkey);
            published = localkey;
        }
    }
    if (localkey < published) atomicMin(&keys[pix], localkey);
}

// Launch 4: resolve + shade; 64 lanes per pixel (lane = channel), 4 pixels/block.
// Reads the stored record rec0[fid] (bit-exact transformed verts; no recompute).
__global__ __launch_bounds__(256) void k_post(const ull* __restrict__ keys,
        const float* __restrict__ rec0, const float* __restrict__ feats,
        const int* __restrict__ faces, float* __restrict__ out){
    int grp = threadIdx.x >> 6;
    int c = threadIdx.x & 63;
    int pix = blockIdx.x*4 + grp;
    float* p2f  = out + OFF_P2F;
    float* zbuf = out + OFF_ZBUF;
    float* bary = out + OFF_BARY;
    float* dist = out + OFF_DIST;
    ull key = keys[pix];
    if (key == 0xFFFFFFFFFFFFFFFFULL){
        out[OFF_FEATS + pix*C_ + c] = 0.0f;
        if (c == 0){
            p2f[pix] = -1.0f; zbuf[pix] = -1.0f; dist[pix] = -1.0f;
        }
        if (c < 3) bary[3*pix+c] = -1.0f;
        return;
    }
    int f = (int)(key & 0xFFFFFFFFu);
    float z = __uint_as_float((unsigned)(key >> 32));
    int ix = pix % W_, iy = pix / W_;
    float px = pixcoord(ix, (float)W_);
    float py = pixcoord(iy, (float)H_);
    const float4* q = (const float4*)(rec0 + (size_t)f*12);
    float4 q0 = q[0], q1 = q[1], q2 = q[2];
    float x0=q0.x, y0=q0.y, x1=q0.z, y1=q0.w;
    float x2=q1.x, y2=q1.y, z0=q1.z, z1=q1.w;
    float z2=q2.x, ia=q2.y;
    float w0 = xm(xsb(xm(xsb(x1,px),xsb(y2,py)), xm(xsb(y1,py),xsb(x2,px))), ia);
    float w1 = xm(xsb(xm(xsb(x2,px),xsb(y0,py)), xm(xsb(y2,py),xsb(x0,px))), ia);
    float w2 = xm(xsb(xm(xsb(x0,px),xsb(y1,py)), xm(xsb(y0,py),xsb(x1,px))), ia);
    float l0 = xm(xm(w0,z1),z2);
    float l1 = xm(xm(z0,w1),z2);
    float l2 = xm(xm(z0,z1),w2);
    float s  = xa(xa(l0,l1),l2);
    float dn = (s == 0.f) ? 1.0f : s;
    float b0 = fmaxf(xd(l0,dn), 0.f);
    float b1 = fmaxf(xd(l1,dn), 0.f);
    float b2 = fmaxf(xd(l2,dn), 0.f);
    float bs = fmaxf(xa(xa(b0,b1),b2), EPS_F);
    b0 = xd(b0,bs); b1 = xd(b1,bs); b2 = xd(b2,bs);
    int i0 = faces[3*f+0], i1 = faces[3*f+1], i2 = faces[3*f+2];
    float res = xa(xa(xm(b0, feats[i0*C_ + c]), xm(b1, feats[i1*C_ + c])),
                   xm(b2, feats[i2*C_ + c]));
    out[OFF_FEATS + pix*C_ + c] = res;
    if (c == 0){
        p2f[pix] = (float)f; zbuf[pix] = z; dist[pix] = 0.0f;
    }
    if (c < 3){
        float bb = (c == 0) ? b0 : ((c == 1) ? b1 : b2);
        bary[3*pix+c] = bb;
    }
}

extern "C" void kernel_launch(void* const* d_in, const int* in_sizes, int n_in,
                              void* d_out, int out_size, void* d_ws, size_t ws_size,
                              hipStream_t stream) {
    const float* positions = (const float*)d_in[0];
    const float* features  = (const float*)d_in[1];
    const int*   faces     = (const int*)  d_in[2];
    const float* K         = (const float*)d_in[3];
    const float* RT        = (const float*)d_in[4];
    int Fn = in_sizes[2] / 3;   // 16384

    // Workspace (memset-friendly ordering):
    // region A (0xFF): keys | chunkmin | gbbmin   region B (0x00): hist | histcur | gbbmax
    ull*      keys     = (ull*)d_ws;                    // H*W * 8 B
    unsigned* chunkmin = (unsigned*)(keys + H_*W_);     // 64 words
    unsigned* gbbmin   = chunkmin + MAXCHUNK;           // 4 words (2 used + pad)
    unsigned* hist     = gbbmin + 4;                    // 256 words
    unsigned* histcur  = hist + NBUCKET;                // 256 words
    unsigned* gbbmax   = histcur + NBUCKET;             // 4 words (2 used + pad)
    float*    rec      = (float*)(gbbmax + 4);          // Fn*20 floats (depth-sorted)
    float*    rec0     = rec + (size_t)Fn*20;           // Fn*12 floats (unsorted)

    size_t regA = (size_t)H_*W_*sizeof(ull) + MAXCHUNK*4 + 16;
    size_t regB = NBUCKET*4*2 + 16;
    hipMemsetAsync(keys, 0xFF, regA, stream);
    hipMemsetAsync(hist, 0x00, regB, stream);

    int nfb = (Fn + 255) / 256;
    k_pre<<<(Fn+63)/64, 64, 0, stream>>>(positions, K, RT, faces, rec0, hist, gbbmin, gbbmax, Fn);
    k_scatter<<<nfb, 256, 0, stream>>>(rec0, hist, histcur, rec, chunkmin, Fn);
    dim3 rg(NTX, NTY, NSLICE);
    k_raster<<<rg, dim3(256,1,1), 0, stream>>>(rec, chunkmin, gbbmin, gbbmax, keys, Fn);
    k_post<<<(H_*W_)/4, 256, 0, stream>>>(keys, rec0, features, faces, (float*)d_out);
}

// Round 6
// 141.869 us; speedup vs baseline: 2.6900x; 1.4365x over previous
//
#include <hip/hip_runtime.h>
#include <stdint.h>

#define H_ 192
#define W_ 192
#define C_ 64
#define EPS_F 1e-8f
#define TILE 16
#define NTX (W_/TILE)
#define NTY (H_/TILE)
#define CHUNK 256
#define NSLICE 8
#define NBUCKET 256
#define MAXCHUNK 64

typedef unsigned long long ull;

// Output layout (floats), concatenated in reference return order:
// feats (H*W*C) | p2f (H*W) | zbuf (H*W) | bary (H*W*3) | dists (H*W)
#define OFF_FEATS 0
#define OFF_P2F   (H_*W_*C_)
#define OFF_ZBUF  (OFF_P2F + H_*W_)
#define OFF_BARY  (OFF_ZBUF + H_*W_)
#define OFF_DIST  (OFF_BARY + H_*W_*3)

// IEEE-exact ops (block FMA contraction; match numpy float32 op-for-op)
__device__ __forceinline__ float xm(float a, float b){ return __fmul_rn(a,b); }
__device__ __forceinline__ float xa(float a, float b){ return __fadd_rn(a,b); }
__device__ __forceinline__ float xsb(float a, float b){ return __fsub_rn(a,b); }
__device__ __forceinline__ float xd(float a, float b){ return __fdiv_rn(a,b); }

__device__ __forceinline__ float pixcoord(int i, float dim){
    float t = xa(xm(2.0f, (float)i), 1.0f);
    return xsb(1.0f, xd(t, dim));
}

// monotone float<->uint encode for signed-float atomic min/max
__device__ __forceinline__ unsigned fenc(float f){
    unsigned b = __float_as_uint(f);
    return (b & 0x80000000u) ? ~b : (b | 0x80000000u);
}
__device__ __forceinline__ float fdec(unsigned e){
    unsigned b = (e & 0x80000000u) ? (e & 0x7FFFFFFFu) : ~e;
    return __uint_as_float(b);
}

// depth bucket: fixed mapping. zlo(b) below must lower-bound every zmin in b.
__device__ __forceinline__ int zbucket(float zmn){
    int b = (int)((zmn - 2.0f) * 64.0f);
    return b < 0 ? 0 : (b > 254 ? 254 : b);
}
__device__ __forceinline__ float zlo_bucket(int b){
    if (b >= 255) return INFINITY;      // dead bucket (or beyond end)
    if (b == 0)   return 0.0f;          // bucket 0 catches all small z
    return 2.0f + (float)b * 0.015625f; // faces in b have zmin >= 2 + b/64
}

// Vertex transform — computed ONCE (k_pre); consumers read the stored bits.
__device__ __forceinline__ float3 tv(const float* __restrict__ pos,
        const float* __restrict__ K, const float* __restrict__ RT, int i){
    float p0 = pos[3*i+0], p1 = pos[3*i+1], p2 = pos[3*i+2];
    const float sgn[3] = {-1.f, -1.f, 1.f};
    float vv[3];
    #pragma unroll
    for (int j=0;j<3;j++){
        float rp0 = xm(RT[j*4+0], sgn[j]);
        float rp1 = xm(RT[j*4+1], sgn[j]);
        float rp2 = xm(RT[j*4+2], sgn[j]);
        float s = xa(xa(xm(p0,rp0), xm(p1,rp1)), xm(p2,rp2));
        vv[j] = xa(s, xm(RT[j*4+3], sgn[j]));
    }
    float z = vv[2];
    float fx = xd(K[0], 96.0f);
    float fy = xd(K[4], 96.0f);
    float p0x = -xd(xsb(K[2], 96.0f), 96.0f);
    float p0y = -xd(xsb(K[5], 96.0f), 96.0f);
    float xn = xa(xd(xm(fx, vv[0]), z), p0x);
    float yn = xa(xd(xm(fy, vv[1]), z), p0y);
    return make_float3(xn, yn, z);
}

// Launch 1 (256 blocks x 64 thr): transform verts once, write unsorted record
// rec0[f], LDS histogram -> non-returning global adds, wave-reduced bbox.
// rec0 (3 float4): q0 x0,y0,x1,y1 | q1 x2,y2,z0,z1 | q2 z2,ia,fid,zmin
__global__ __launch_bounds__(64) void k_pre(const float* __restrict__ pos,
        const float* __restrict__ K, const float* __restrict__ RT,
        const int* __restrict__ faces, float* __restrict__ rec0,
        unsigned* __restrict__ hist, unsigned* __restrict__ gbbmin,
        unsigned* __restrict__ gbbmax, int Fn){
    __shared__ unsigned lh[NBUCKET];
    int t = threadIdx.x, B = blockIdx.x;
    #pragma unroll
    for (int i=t; i<NBUCKET; i+=64) lh[i] = 0u;
    __syncthreads();
    int f = B*64 + t;
    float bxmn=INFINITY, bxmx=-INFINITY, bymn=INFINITY, bymx=-INFINITY;
    if (f < Fn){
        int i0 = faces[3*f+0], i1 = faces[3*f+1], i2 = faces[3*f+2];
        float3 v0 = tv(pos,K,RT,i0), v1 = tv(pos,K,RT,i1), v2 = tv(pos,K,RT,i2);
        float area = xsb(xm(xsb(v1.x,v0.x), xsb(v2.y,v0.y)), xm(xsb(v1.y,v0.y), xsb(v2.x,v0.x)));
        bool ok = (area > EPS_F) && (v0.z > 0.f) && (v1.z > 0.f) && (v2.z > 0.f);
        float ia = ok ? xd(1.0f, area) : 0.0f;
        float zmn = INFINITY;
        int b = 255;
        if (ok){
            zmn = fminf(v0.z, fminf(v1.z, v2.z));
            b = zbucket(zmn);
            bxmn = fminf(v0.x, fminf(v1.x, v2.x)) - 1e-4f;
            bxmx = fmaxf(v0.x, fmaxf(v1.x, v2.x)) + 1e-4f;
            bymn = fminf(v0.y, fminf(v1.y, v2.y)) - 1e-4f;
            bymx = fmaxf(v0.y, fmaxf(v1.y, v2.y)) + 1e-4f;
        }
        atomicAdd(&lh[b], 1u);
        float4* q = (float4*)(rec0 + (size_t)f*12);
        q[0] = make_float4(v0.x, v0.y, v1.x, v1.y);
        q[1] = make_float4(v2.x, v2.y, v0.z, v1.z);
        q[2] = make_float4(v2.z, ia, __int_as_float(f), zmn);
    }
    // single-wave bbox reduce -> 4 non-returning atomics per block
    #pragma unroll
    for (int s2=1; s2<64; s2<<=1){
        bxmn = fminf(bxmn, __shfl_xor(bxmn, s2, 64));
        bxmx = fmaxf(bxmx, __shfl_xor(bxmx, s2, 64));
        bymn = fminf(bymn, __shfl_xor(bymn, s2, 64));
        bymx = fmaxf(bymx, __shfl_xor(bymx, s2, 64));
    }
    if (t == 0){
        atomicMin(&gbbmin[0], fenc(bxmn));
        atomicMax(&gbbmax[0], fenc(bxmx));
        atomicMin(&gbbmin[1], fenc(bymn));
        atomicMax(&gbbmax[1], fenc(bymx));
    }
    __syncthreads();
    #pragma unroll
    for (int i=t; i<NBUCKET; i+=64){
        unsigned cc = lh[i];
        if (cc) atomicAdd(&hist[i], cc);   // non-returning, <=256 contenders
    }
}

// Launch 2 (64 blocks x 256): read summed hist, LDS scan, LDS-rank +
// one returning global atomic per (block,bucket), permute rec0 -> depth-sorted
// rec. Block 0 also derives analytic chunk z-bounds suffz[] from the scan
// (replaces the old 16K-atomic chunkmin — zero global atomics now).
// rec: q0 x0,y0,x1,y1 | q1 x2,y2,z0,z1 | q2 z2,ia,fid,zmin | q3 A,B,C,0 | q4 xmn,xmx,ymn,ymx
__global__ __launch_bounds__(256) void k_scatter(const float* __restrict__ rec0,
        const unsigned* __restrict__ hist, unsigned* __restrict__ histcur,
        float* __restrict__ rec, float* __restrict__ suffz, int Fn){
    __shared__ unsigned gst[NBUCKET], ssc[NBUCKET], lcnt[NBUCKET], lbase[NBUCKET];
    int t = threadIdx.x, B = blockIdx.x;
    unsigned hv = hist[t];
    ssc[t] = hv;
    lcnt[t] = 0u;
    __syncthreads();
    for (int d=1; d<NBUCKET; d<<=1){
        unsigned u = (t >= d) ? ssc[t-d] : 0u;
        __syncthreads();
        ssc[t] += u;
        __syncthreads();
    }
    gst[t] = ssc[t] - hv;   // exclusive global bucket start
    __syncthreads();
    // Block 0: suffz[c] = zlo(bucket containing sorted position c*CHUNK).
    // Buckets ascend in z, so this is simultaneously the suffix-min bound:
    // every face at position >= c*CHUNK has zmin >= suffz[c].
    if (B == 0 && t < MAXCHUNK){
        unsigned pos = (unsigned)t * CHUNK;
        int bb = 0;
        #pragma unroll
        for (int s = 128; s > 0; s >>= 1){
            int nb = bb + s;
            if (nb <= NBUCKET && ssc[nb-1] <= pos) bb = nb;
        }
        suffz[t] = zlo_bucket(bb);   // bb==256 (pos>=Fn) -> INF via >=255
    }
    int f = B*256 + t;
    bool valid = (f < Fn);
    float4 q0, q1, q2;
    int b = 255; unsigned rank = 0; bool ok = false; float zmn = INFINITY;
    if (valid){
        const float4* q = (const float4*)(rec0 + (size_t)f*12);
        q0 = q[0]; q1 = q[1]; q2 = q[2];
        ok = (q2.y > 0.f);            // ia > 0 <=> face live
        zmn = q2.w;
        b = ok ? zbucket(zmn) : 255;
        rank = atomicAdd(&lcnt[b], 1u);     // LDS intra-block rank
    }
    __syncthreads();
    unsigned add = lcnt[t];
    if (add) lbase[t] = atomicAdd(&histcur[t], add);  // one per (block,bucket)
    __syncthreads();
    if (valid){
        float x0=q0.x, y0=q0.y, x1=q0.z, y1=q0.w;
        float x2=q1.x, y2=q1.y, z0=q1.z, z1=q1.w;
        float z2=q2.x, ia=q2.y;
        float xmn, xmx, ymn, ymx, Ap=0.f, Bp=0.f, Cp=0.f;
        if (ok){
            xmn = fminf(x0, fminf(x1, x2)) - 1e-4f;
            xmx = fmaxf(x0, fmaxf(x1, x2)) + 1e-4f;
            ymn = fminf(y0, fminf(y1, y2)) - 1e-4f;
            ymx = fmaxf(y0, fmaxf(y1, y2)) + 1e-4f;
            // 1/zp = C + A*px + B*py  (filter-only; margins absorb FP error)
            float iz0 = 1.f/z0, iz1 = 1.f/z1, iz2 = 1.f/z2;
            Ap = ia * ((y1-y2)*iz0 + (y2-y0)*iz1 + (y0-y1)*iz2);
            Bp = ia * ((x2-x1)*iz0 + (x0-x2)*iz1 + (x1-x0)*iz2);
            Cp = ia * ((x1*y2-x2*y1)*iz0 + (x2*y0-x0*y2)*iz1 + (x0*y1-x1*y0)*iz2);
        } else {
            xmn = INFINITY; xmx = -INFINITY; ymn = INFINITY; ymx = -INFINITY;
        }
        unsigned p = gst[b] + lbase[b] + rank;   // unique depth-sorted slot
        float4* qo = (float4*)(rec + (size_t)p*20);
        qo[0] = q0; qo[1] = q1; qo[2] = q2;
        qo[3] = make_float4(Ap, Bp, Cp, 0.f);
        qo[4] = make_float4(xmn, xmx, ymn, ymx);
    }
}

// Launch 3: tiled raster (1152 blocks). All skips provably conservative vs the
// FINAL key (zcut >= final zbest always), so output is timing-independent.
__global__ __launch_bounds__(256) void k_raster(const float* __restrict__ rec,
        const float* __restrict__ suffz, const unsigned* __restrict__ gbbmin,
        const unsigned* __restrict__ gbbmax, ull* __restrict__ keys, int Fn){
    __shared__ float lds[CHUNK*12];
    __shared__ float zl[CHUNK];       // per-tile z lower bound of survivors
    __shared__ int   slist[CHUNK];
    __shared__ int   wcnt[4];
    __shared__ float suff[MAXCHUNK];  // analytic chunk z-bounds (already suffix-min)
    int tid = threadIdx.x;
    int nchunk = (Fn + CHUNK - 1) / CHUNK;
    if (tid < MAXCHUNK) suff[tid] = suffz[tid];
    int ix = blockIdx.x*TILE + (tid & 15);
    int iy = blockIdx.y*TILE + (tid >> 4);
    int pix = iy*W_ + ix;
    float px = pixcoord(ix, (float)W_);
    float py = pixcoord(iy, (float)H_);
    float tx_hi = pixcoord(blockIdx.x*TILE,          (float)W_);
    float tx_lo = pixcoord(blockIdx.x*TILE + TILE-1, (float)W_);
    float ty_hi = pixcoord(blockIdx.y*TILE,          (float)H_);
    float ty_lo = pixcoord(blockIdx.y*TILE + TILE-1, (float)H_);
    float gx0 = fdec(gbbmin[0]), gx1 = fdec(gbbmax[0]);
    float gy0 = fdec(gbbmin[1]), gy1 = fdec(gbbmax[1]);
    bool alive = (px >= gx0) && (px <= gx1) && (py >= gy0) && (py <= gy1);
    int lane = tid & 63, wv = tid >> 6;

    float zcut = INFINITY;
    ull localkey = 0xFFFFFFFFFFFFFFFFULL;
    ull published = 0xFFFFFFFFFFFFFFFFULL;
    __syncthreads();             // suff[] ready

    for (int c = (int)blockIdx.z; c < nchunk; c += NSLICE){
        // share depth convergence across slice blocks (stale reads conservative)
        ull g = __hip_atomic_load(&keys[pix], __ATOMIC_RELAXED, __HIP_MEMORY_SCOPE_AGENT);
        float zg = __uint_as_float((unsigned)(g >> 32));   // NaN if empty -> fminf ignores
        zcut = fminf(zcut, zg);
        float sc = (c < MAXCHUNK) ? suff[c] : 0.0f;
        int done = (!alive || !(xm(sc, 0.999f) < zcut)) ? 1 : 0;
        if (__syncthreads_and(done)) break;    // barrier also protects lds reuse

        int fi = c*CHUNK + tid;
        float4 q0 = make_float4(0,0,0,0), q1 = q0, q2 = q0;
        bool keep = false;
        float zb = 0.f;
        if (fi < Fn){
            const float4* gq = (const float4*)(rec + (size_t)fi*20);
            q0 = gq[0]; q1 = gq[1]; q2 = gq[2];
            float4 q3 = gq[3], q4 = gq[4];
            keep = (q4.x <= tx_hi) && (q4.y >= tx_lo) && (q4.z <= ty_hi) && (q4.w >= ty_lo);
            if (keep){
                // tile z lower bound from the linear 1/z plane (corner max + margin)
                float ax = (q3.x > 0.f) ? tx_hi : tx_lo;
                float by = (q3.y > 0.f) ? ty_hi : ty_lo;
                float Nmax = q3.z + q3.x*ax + q3.y*by;
                float M = fabsf(q3.x*ax) + fabsf(q3.y*by) + fabsf(q3.z);
                float Nub = Nmax + 1e-5f*M + 1e-30f;
                if (Nub <= 0.f) keep = false;          // no coverage possible in tile
                else zb = fmaxf(1.f/Nub, q2.w);        // max(plane bound, face zmin)
            }
        }
        float4* l = (float4*)(lds + tid*12);
        l[0] = q0; l[1] = q1; l[2] = q2;
        ull m = __ballot(keep);
        if (lane == 0) wcnt[wv] = __popcll(m);
        __syncthreads();
        int basecnt = 0;
        #pragma unroll
        for (int w2 = 0; w2 < 4; ++w2) if (w2 < wv) basecnt += wcnt[w2];
        if (keep){
            int p = basecnt + __popcll(m & ((1ULL << lane) - 1ULL));
            slist[p] = tid;
            zl[p] = zb;
        }
        int nsurv = wcnt[0] + wcnt[1] + wcnt[2] + wcnt[3];
        __syncthreads();

        for (int k = 0; k < nsurv; k++){
            float zbl = zl[k];
            if (!(xm(zbl, 0.999f) < zcut)) continue;   // conservative tile-z pre-check
            int j = slist[k];
            const float* r = lds + j*12;
            float x0=r[0], y0=r[1], x1=r[2], y1=r[3], x2=r[4], y2=r[5];
            float dx0=xsb(x0,px), dx1=xsb(x1,px), dx2=xsb(x2,px);
            float dy0=xsb(y0,py), dy1=xsb(y1,py), dy2=xsb(y2,py);
            float e0 = xsb(xm(dx1,dy2), xm(dy1,dx2));
            float e1 = xsb(xm(dx2,dy0), xm(dy2,dx0));
            float e2 = xsb(xm(dx0,dy1), xm(dy0,dx1));
            if (e0 >= 0.f && e1 >= 0.f && e2 >= 0.f){
                float z0=r[6], z1=r[7], z2=r[8], ia=r[9];
                float w0 = xm(e0, ia), w1 = xm(e1, ia), w2 = xm(e2, ia);
                float l0 = xm(xm(w0,z1),z2);
                float l1 = xm(xm(z0,w1),z2);
                float l2 = xm(xm(z0,z1),w2);
                float s  = xa(xa(l0,l1),l2);
                // cheap-z filter (1 divide); skip only when provably worse than zcut.
                float za = (l0*z0 + l1*z1 + l2*z2) / s;
                if (za*0.99999f >= zcut) continue;
                float dn = (s == 0.f) ? 1.0f : s;
                float b0 = fmaxf(xd(l0,dn), 0.f);
                float b1 = fmaxf(xd(l1,dn), 0.f);
                float b2 = fmaxf(xd(l2,dn), 0.f);
                float bs = fmaxf(xa(xa(b0,b1),b2), EPS_F);
                b0 = xd(b0,bs); b1 = xd(b1,bs); b2 = xd(b2,bs);
                float zp = xa(xa(xm(b0,z0),xm(b1,z1)),xm(b2,z2));
                // packed (z, orig_fid) key: exact argmin-first tie semantics
                ull ck = (((ull)__float_as_uint(zp)) << 32) | (unsigned)__float_as_int(r[10]);
                if (ck < localkey) localkey = ck;
                zcut = fminf(zcut, zp);
            }
        }
        if (localkey < published){     // publish so other slice blocks can break
            atomicMin(&keys[pix], localkey);
            published = localkey;
        }
    }
    if (localkey < published) atomicMin(&keys[pix], localkey);
}

// Launch 4: resolve + shade; 64 lanes per pixel (lane = channel), 4 pixels/block.
// Reads the stored record rec0[fid] (bit-exact transformed verts; no recompute).
__global__ __launch_bounds__(256) void k_post(const ull* __restrict__ keys,
        const float* __restrict__ rec0, const float* __restrict__ feats,
        const int* __restrict__ faces, float* __restrict__ out){
    int grp = threadIdx.x >> 6;
    int c = threadIdx.x & 63;
    int pix = blockIdx.x*4 + grp;
    float* p2f  = out + OFF_P2F;
    float* zbuf = out + OFF_ZBUF;
    float* bary = out + OFF_BARY;
    float* dist = out + OFF_DIST;
    ull key = keys[pix];
    if (key == 0xFFFFFFFFFFFFFFFFULL){
        out[OFF_FEATS + pix*C_ + c] = 0.0f;
        if (c == 0){
            p2f[pix] = -1.0f; zbuf[pix] = -1.0f; dist[pix] = -1.0f;
        }
        if (c < 3) bary[3*pix+c] = -1.0f;
        return;
    }
    int f = (int)(key & 0xFFFFFFFFu);
    float z = __uint_as_float((unsigned)(key >> 32));
    int ix = pix % W_, iy = pix / W_;
    float px = pixcoord(ix, (float)W_);
    float py = pixcoord(iy, (float)H_);
    const float4* q = (const float4*)(rec0 + (size_t)f*12);
    float4 q0 = q[0], q1 = q[1], q2 = q[2];
    float x0=q0.x, y0=q0.y, x1=q0.z, y1=q0.w;
    float x2=q1.x, y2=q1.y, z0=q1.z, z1=q1.w;
    float z2=q2.x, ia=q2.y;
    float w0 = xm(xsb(xm(xsb(x1,px),xsb(y2,py)), xm(xsb(y1,py),xsb(x2,px))), ia);
    float w1 = xm(xsb(xm(xsb(x2,px),xsb(y0,py)), xm(xsb(y2,py),xsb(x0,px))), ia);
    float w2 = xm(xsb(xm(xsb(x0,px),xsb(y1,py)), xm(xsb(y0,py),xsb(x1,px))), ia);
    float l0 = xm(xm(w0,z1),z2);
    float l1 = xm(xm(z0,w1),z2);
    float l2 = xm(xm(z0,z1),w2);
    float s  = xa(xa(l0,l1),l2);
    float dn = (s == 0.f) ? 1.0f : s;
    float b0 = fmaxf(xd(l0,dn), 0.f);
    float b1 = fmaxf(xd(l1,dn), 0.f);
    float b2 = fmaxf(xd(l2,dn), 0.f);
    float bs = fmaxf(xa(xa(b0,b1),b2), EPS_F);
    b0 = xd(b0,bs); b1 = xd(b1,bs); b2 = xd(b2,bs);
    int i0 = faces[3*f+0], i1 = faces[3*f+1], i2 = faces[3*f+2];
    float res = xa(xa(xm(b0, feats[i0*C_ + c]), xm(b1, feats[i1*C_ + c])),
                   xm(b2, feats[i2*C_ + c]));
    out[OFF_FEATS + pix*C_ + c] = res;
    if (c == 0){
        p2f[pix] = (float)f; zbuf[pix] = z; dist[pix] = 0.0f;
    }
    if (c < 3){
        float bb = (c == 0) ? b0 : ((c == 1) ? b1 : b2);
        bary[3*pix+c] = bb;
    }
}

extern "C" void kernel_launch(void* const* d_in, const int* in_sizes, int n_in,
                              void* d_out, int out_size, void* d_ws, size_t ws_size,
                              hipStream_t stream) {
    const float* positions = (const float*)d_in[0];
    const float* features  = (const float*)d_in[1];
    const int*   faces     = (const int*)  d_in[2];
    const float* K         = (const float*)d_in[3];
    const float* RT        = (const float*)d_in[4];
    int Fn = in_sizes[2] / 3;   // 16384

    // Workspace (memset-friendly ordering):
    // region A (0xFF): keys | gbbmin   region B (0x00): hist | histcur | gbbmax
    ull*      keys     = (ull*)d_ws;                    // H*W * 8 B
    unsigned* gbbmin   = (unsigned*)(keys + H_*W_);     // 4 words (2 used + pad)
    unsigned* hist     = gbbmin + 4;                    // 256 words
    unsigned* histcur  = hist + NBUCKET;                // 256 words
    unsigned* gbbmax   = histcur + NBUCKET;             // 4 words (2 used + pad)
    float*    suffz    = (float*)(gbbmax + 4);          // 64 floats (written by scatter blk0)
    float*    rec      = suffz + MAXCHUNK;              // Fn*20 floats (depth-sorted)
    float*    rec0     = rec + (size_t)Fn*20;           // Fn*12 floats (unsorted)

    size_t regA = (size_t)H_*W_*sizeof(ull) + 16;
    size_t regB = (NBUCKET*2 + 4)*4;
    hipMemsetAsync(keys, 0xFF, regA, stream);
    hipMemsetAsync(hist, 0x00, regB, stream);

    int nfb = (Fn + 255) / 256;
    k_pre<<<(Fn+63)/64, 64, 0, stream>>>(positions, K, RT, faces, rec0, hist, gbbmin, gbbmax, Fn);
    k_scatter<<<nfb, 256, 0, stream>>>(rec0, hist, histcur, rec, suffz, Fn);
    dim3 rg(NTX, NTY, NSLICE);
    k_raster<<<rg, dim3(256,1,1), 0, stream>>>(rec, suffz, gbbmin, gbbmax, keys, Fn);
    k_post<<<(H_*W_)/4, 256, 0, stream>>>(keys, rec0, features, faces, (float*)d_out);
}